// Round 1
// baseline (933.578 us; speedup 1.0000x reference)
//
#include <hip/hip_runtime.h>
#include <math.h>

// Problem constants (from reference): B=16, N=325, H=8, L=24, DK=DV=64
#define NB   16
#define NN   325
#define NH   8
#define LL   24
#define DK   64
#define DV   64
#define NG   (NB * NN * NH)          // 41600 independent (b,n,h) tiles
#define STR  68                       // LDS row stride for Q/K/V: 16B-aligned, conflict-free for 3-stepped rows
#define SSTR 25                       // LDS row stride for 24x24 scores (pad +1)

__device__ __forceinline__ float dot4(float4 a, float4 b) {
    return a.x * b.x + a.y * b.y + a.z * b.z + a.w * b.w;
}

__global__ __launch_bounds__(256) void tatt_kernel(
    const float* __restrict__ Q, const float* __restrict__ K,
    const float* __restrict__ V, const float* __restrict__ Mask,
    const float* __restrict__ Res, float* __restrict__ outC,
    float* __restrict__ outS)
{
    __shared__ float sQ[LL * STR];   // 6528 B
    __shared__ float sK[LL * STR];   // 6528 B
    __shared__ float sV[LL * STR];   // 6528 B
    __shared__ float sS[LL * SSTR];  // 2400 B  scores -> attn (in place)
    __shared__ float sM[LL];         // per-column (k) max over q
    __shared__ float sI[LL];         // per-column (k) 1/sum

    const int g   = blockIdx.x;
    const int tid = threadIdx.x;

    const float* Qg = Q    + (size_t)g * (LL * DK);
    const float* Kg = K    + (size_t)g * (LL * DK);
    const float* Vg = V    + (size_t)g * (LL * DV);
    const float* Mg = Mask + (size_t)g * (LL * LL);
    const float* Rg = Res  + (size_t)g * (LL * LL);
    float*       Cg = outC + (size_t)g * (LL * DV);
    float*       Sg = outS + (size_t)g * (LL * LL);

    // ---- Phase 1: stage Q,K,V into LDS (fully coalesced float4) ----
    // 3 matrices x 24 rows x 16 float4 = 1152 float4 items
    #pragma unroll
    for (int ii = 0; ii < 5; ++ii) {
        int i = tid + ii * 256;
        if (i < 1152) {
            int m   = i / 384;
            int j   = i - m * 384;
            int row = j >> 4;
            int c   = (j & 15) << 2;
            const float* src = (m == 0) ? Qg : (m == 1) ? Kg : Vg;
            float*       dst = (m == 0) ? sQ : (m == 1) ? sK : sV;
            float4 val = *(const float4*)(src + row * DK + c);
            *(float4*)(dst + row * STR + c) = val;
        }
    }
    __syncthreads();

    // ---- Phase 2: S = Q.K^T / 8 + Res, masked. One wave, 3x3 register tiles ----
    if (tid < 64) {
        const int q0 = (tid >> 3) * 3;   // 8 q-triples
        const int k0 = (tid & 7) * 3;    // 8 k-triples
        float acc[3][3] = {{0.f,0.f,0.f},{0.f,0.f,0.f},{0.f,0.f,0.f}};
        for (int d = 0; d < DK; d += 4) {
            float4 qv0 = *(const float4*)(sQ + (q0 + 0) * STR + d);
            float4 qv1 = *(const float4*)(sQ + (q0 + 1) * STR + d);
            float4 qv2 = *(const float4*)(sQ + (q0 + 2) * STR + d);
            float4 kv0 = *(const float4*)(sK + (k0 + 0) * STR + d);
            float4 kv1 = *(const float4*)(sK + (k0 + 1) * STR + d);
            float4 kv2 = *(const float4*)(sK + (k0 + 2) * STR + d);
            acc[0][0] += dot4(qv0, kv0); acc[0][1] += dot4(qv0, kv1); acc[0][2] += dot4(qv0, kv2);
            acc[1][0] += dot4(qv1, kv0); acc[1][1] += dot4(qv1, kv1); acc[1][2] += dot4(qv1, kv2);
            acc[2][0] += dot4(qv2, kv0); acc[2][1] += dot4(qv2, kv1); acc[2][2] += dot4(qv2, kv2);
        }
        #pragma unroll
        for (int r = 0; r < 3; ++r) {
            #pragma unroll
            for (int c = 0; c < 3; ++c) {
                int q = q0 + r, k = k0 + c;
                float s = acc[r][c] * 0.125f + Rg[q * LL + k];
                s = (Mg[q * LL + k] > 0.5f) ? -1e9f : s;
                sS[q * SSTR + k] = s;
            }
        }
    }
    __syncthreads();

    // ---- Phase 3 (parallel, read-only on sS):
    //      tid<144: write masked scores to global (coalesced float4 gather)
    //      tid in [192,216): per-column (k) softmax stats over q (axis=3!)
    if (tid < 144) {
        int i0 = tid * 4;
        float4 o;
        {
            int i = i0 + 0; int q = i / LL, k = i - q * LL; o.x = sS[q * SSTR + k];
        }
        {
            int i = i0 + 1; int q = i / LL, k = i - q * LL; o.y = sS[q * SSTR + k];
        }
        {
            int i = i0 + 2; int q = i / LL, k = i - q * LL; o.z = sS[q * SSTR + k];
        }
        {
            int i = i0 + 3; int q = i / LL, k = i - q * LL; o.w = sS[q * SSTR + k];
        }
        *(float4*)(Sg + i0) = o;
    } else if (tid >= 192 && tid < 192 + LL) {
        int k = tid - 192;
        float m = -INFINITY;
        #pragma unroll
        for (int q = 0; q < LL; ++q) m = fmaxf(m, sS[q * SSTR + k]);
        float sum = 0.f;
        #pragma unroll
        for (int q = 0; q < LL; ++q) sum += __expf(sS[q * SSTR + k] - m);
        sM[k] = m;
        sI[k] = 1.f / sum;
    }
    __syncthreads();

    // ---- Phase 4: A = exp(S - m_col) * inv_sum_col, in place ----
    #pragma unroll
    for (int ii = 0; ii < 3; ++ii) {
        int i = tid + ii * 256;
        if (i < LL * LL) {
            int q = i / LL, k = i - q * LL;
            sS[q * SSTR + k] = __expf(sS[q * SSTR + k] - sM[k]) * sI[k];
        }
    }
    __syncthreads();

    // ---- Phase 5: C[q][v] = sum_k A[q][k] * V[k][v]. 2q x 4v register tiles ----
    if (tid < 192) {
        const int q0 = (tid >> 4) * 2;   // 12 q-pairs
        const int v0 = (tid & 15) * 4;   // 16 v-quads
        float4 acc0 = {0.f, 0.f, 0.f, 0.f};
        float4 acc1 = {0.f, 0.f, 0.f, 0.f};
        for (int k = 0; k < LL; ++k) {
            float a0 = sS[(q0 + 0) * SSTR + k];
            float a1 = sS[(q0 + 1) * SSTR + k];
            float4 vv = *(const float4*)(sV + k * STR + v0);
            acc0.x += a0 * vv.x; acc0.y += a0 * vv.y; acc0.z += a0 * vv.z; acc0.w += a0 * vv.w;
            acc1.x += a1 * vv.x; acc1.y += a1 * vv.y; acc1.z += a1 * vv.z; acc1.w += a1 * vv.w;
        }
        *(float4*)(Cg + (q0 + 0) * DV + v0) = acc0;
        *(float4*)(Cg + (q0 + 1) * DV + v0) = acc1;
    }
}

extern "C" void kernel_launch(void* const* d_in, const int* in_sizes, int n_in,
                              void* d_out, int out_size, void* d_ws, size_t ws_size,
                              hipStream_t stream) {
    const float* Q    = (const float*)d_in[0];
    const float* K    = (const float*)d_in[1];
    const float* V    = (const float*)d_in[2];
    const float* Mask = (const float*)d_in[3];
    const float* Res  = (const float*)d_in[4];
    float* outC = (float*)d_out;                              // context: G*L*DV
    float* outS = (float*)d_out + (size_t)NG * LL * DV;       // scores:  G*L*L
    hipLaunchKernelGGL(tatt_kernel, dim3(NG), dim3(256), 0, stream,
                       Q, K, V, Mask, Res, outC, outS);
}